// Round 9
// baseline (7858.555 us; speedup 1.0000x reference)
//
#include <hip/hip_runtime.h>
#include <cstdint>
#include <cstddef>

// ECPEC pipeline for MI355X (gfx950) — f32 everywhere (upstream precision is
// load-bearing: the alpha-denominator amplifies rounding ~1e6x; bf16 fails).
// R9: persistent LSTM chunk kernel with FIXED barrier (padded per-group
// counters, acquire/release atomics, read-only polling) and non-temporal
// Hs stores / gch loads (keep wp L2-resident). Math identical to R8.

#define DEV __device__ __forceinline__
typedef float f32x4 __attribute__((ext_vector_type(4)));

// ---------------------------------------------------------------- f32 GEMM
// C[M,N] = A[M,K] @ B[N,K]^T ; tile 128x128, BK=32, 512 threads, 4x8 acc/thread.
// All threads stage 8 A-floats and 8 B-floats per tile (k-major LDS).
// Per-output accumulation order = k ascending (bitwise-stable across tilings).
// AMODE: 0 plain A ; 1 gate-gather fwd ; 3 gate-gather rev ; 2 A=E[e]*Cu[j] ;
//        4 phase-2 fold (ce | E*ce | pos | 0)
// EPI:   0 acc(+bias?) ; 2 lrelu(acc+bias) ; 3 score partials ; 4 phase-2 ; 5 phase-3
struct G32 {
    const float* A;
    const float* B;
    float* out;
    const float* bias;
    const float* s2v;
    float* escoreP;      // [M][6] partials (EPI 3)
    const float* addE;
    const float* addB;
    const float* nrm;
    const float* wn;
    const float* feat;
    const float* wx;
    const float* ce;
    const float* CuEf;
    const float* pos;
    const int* slen;
    int M, N, K, lda, ldb, ldc, c0;
};

template <int AMODE, int EPI>
__global__ __launch_bounds__(512) void k_gemm32(G32 p) {
    __shared__ __align__(16) float As[32][132];  // [kk][m]
    __shared__ __align__(16) float Bs[32][132];  // [kk][n]
    const int tid = threadIdx.x;
    const int tx = tid & 15, ty = tid >> 4;      // ty 0..31
    const int m0 = blockIdx.y * 128, n0 = blockIdx.x * 128;
    float acc[4][8] = {};
    const int ra = tid >> 2;          // 0..127
    const int ka = (tid & 3) * 8;     // 0,8,16,24
    const int gmA = m0 + ra;

    const float* arow = nullptr;
    const float* er = nullptr;
    const float* cr = nullptr;
    const float* prow = nullptr;
    if constexpr (AMODE == 0) {
        arow = p.A + (size_t)gmA * p.lda;
    } else if constexpr (AMODE == 1 || AMODE == 3) {
        int b = gmA >> 5, t = p.c0 + (gmA & 31);
        if constexpr (AMODE == 3) {
            int len = p.slen[b];
            t = (t < len) ? len - 1 - t : t;
        }
        arow = p.A + ((size_t)b * 96 + t) * 768;
    } else if constexpr (AMODE == 2) {
        int e = gmA >> 8, j = gmA & 255;
        er = p.CuEf + (size_t)(256 + e) * 768;
        cr = p.CuEf + (size_t)j * 768;
    } else if constexpr (AMODE == 4) {
        er = p.CuEf + (size_t)(256 + (gmA >> 6)) * 768;
        cr = p.ce + (size_t)gmA * 768;
        prow = p.pos + (size_t)gmA * 50;
    }
    const float* brow = p.B + (size_t)(n0 + ra) * p.ldb;

    auto load_tile = [&](int kt, float* av, float* bv) {
        if constexpr (AMODE == 0 || AMODE == 1 || AMODE == 3) {
            const float* ap = arow + kt + ka;
#pragma unroll
            for (int q = 0; q < 8; q++) av[q] = ap[q];
        } else if constexpr (AMODE == 2) {
#pragma unroll
            for (int q = 0; q < 8; q++) av[q] = er[kt + ka + q] * cr[kt + ka + q];
        } else {
#pragma unroll
            for (int q = 0; q < 8; q++) {
                int k = kt + ka + q;
                float x;
                if (k < 768) x = cr[k];
                else if (k < 1536) x = er[k - 768] * cr[k - 768];
                else if (k < 1586) x = prow[k - 1536];
                else x = 0.f;
                av[q] = x;
            }
        }
        const float* bp = brow + kt + ka;
#pragma unroll
        for (int q = 0; q < 8; q++) bv[q] = bp[q];
    };

    const int nt = p.K / 32;
    float av[8], bv[8];
    load_tile(0, av, bv);
    for (int t = 0; t < nt; t++) {
        __syncthreads();  // previous compute done reading LDS
#pragma unroll
        for (int q = 0; q < 8; q++) {
            As[ka + q][ra] = av[q];
            Bs[ka + q][ra] = bv[q];
        }
        __syncthreads();
        if (t + 1 < nt) load_tile((t + 1) * 32, av, bv);  // overlap with compute
#pragma unroll
        for (int kk = 0; kk < 32; kk++) {
            float a[4], b[8];
            *(f32x4*)a = *(const f32x4*)&As[kk][ty * 4];
            *(f32x4*)b = *(const f32x4*)&Bs[kk][tx * 4];
            *(f32x4*)(b + 4) = *(const f32x4*)&Bs[kk][64 + tx * 4];
#pragma unroll
            for (int i = 0; i < 4; i++)
#pragma unroll
                for (int j = 0; j < 8; j++) acc[i][j] += a[i] * b[j];
        }
    }

    if constexpr (EPI == 3) {
#pragma unroll
        for (int i = 0; i < 4; i++) {
            float s = 0.f;
#pragma unroll
            for (int j = 0; j < 8; j++) {
                int n = n0 + ((j < 4) ? tx * 4 + j : 64 + tx * 4 + (j - 4));
                float x = acc[i][j] + p.bias[n];
                x = x > 0.f ? x : 0.01f * x;
                s += x * p.s2v[n];
            }
            s += __shfl_xor(s, 1);
            s += __shfl_xor(s, 2);
            s += __shfl_xor(s, 4);
            s += __shfl_xor(s, 8);
            if (tx == 0) {
                int m = m0 + ty * 4 + i;
                p.escoreP[(size_t)m * 6 + blockIdx.x] = s;
            }
        }
    } else {
#pragma unroll
        for (int i = 0; i < 4; i++)
#pragma unroll
            for (int j = 0; j < 8; j++) {
                int m = m0 + ty * 4 + i;
                int n = n0 + ((j < 4) ? tx * 4 + j : 64 + tx * 4 + (j - 4));
                float x = acc[i][j];
                if constexpr (EPI == 0) {
                    if (p.bias) x += p.bias[n];
                } else if constexpr (EPI == 2) {
                    x += p.bias[n];
                    x = x > 0.f ? x : 0.01f * x;
                } else if constexpr (EPI == 4) {
                    int e = m >> 6;
                    x += p.addE[(size_t)e * 768 + n] + p.nrm[m] * p.wn[n] + p.bias[n];
                } else if constexpr (EPI == 5) {
                    int e = m >> 8, jj = m & 255;
                    float ex = p.feat[e * 64 + (jj >> 2)];
                    x += p.addE[(size_t)e * 768 + n] + p.addB[(size_t)jj * 768 + n] +
                         p.nrm[m] * p.wn[n] + ex * p.wx[n];
                }
                p.out[(size_t)m * p.ldc + n] = x;
            }
    }
}

// ---------------------------------------------------------------- Whh pack
// Wpack[k][u*4+g] = Whh[g*384+u][k]  (one coalesced f32x4 per thread per k)
__global__ void k_wpack(const float* __restrict__ whh, float* __restrict__ wp) {
    int idx = blockIdx.x * 256 + threadIdx.x;
    if (idx < 384 * 1536) {
        int k = idx / 1536, rem = idx - k * 1536;
        int u = rem >> 2, g = rem & 3;
        wp[idx] = whh[(size_t)(g * 384 + u) * 384 + k];
    }
}

// ---------------------------------------------------------------- LSTM chunk
// Persistent: 32 steps per launch. Grid (12, 8, 2) = 192 blocks of 512 threads
// (32 units x 32 rows, 2 rows/thread). Per-step group barrier over the 12
// u-tile blocks sharing (r-tile, dir): padded per-group counters (256 B),
// release fetch_add + acquire read-only polling. Hs stored non-temporally and
// gch loaded non-temporally to keep wp L2-resident. Math identical to R8.
__global__ __launch_bounds__(512) void k_lstm_chunk(
    const float* __restrict__ gchF, const float* __restrict__ gchB,
    const float* __restrict__ wpF, const float* __restrict__ wpB,
    float* __restrict__ hbuf, float* __restrict__ cst, float* __restrict__ Hs,
    const int* __restrict__ slen, unsigned* __restrict__ bar, int c0) {
    __shared__ __align__(16) float hrow[32][384];  // 48 KB
    const int tid = threadIdx.x;
    const int u0 = blockIdx.x * 32;
    const int r0g = blockIdx.y * 32;
    const int dir = blockIdx.z;
    const float* gch = dir ? gchB : gchF;
    const float* wp = dir ? wpB : wpF;
    float* cs = cst + (size_t)dir * 98304;
    unsigned* gbar = bar + (blockIdx.y * 2 + dir) * 64;  // 256 B per group

    const int rr = tid >> 5;          // 0..15
    const int ug = u0 + (tid & 31);   // 32 units
    const float* wpb = wp + (size_t)ug * 4;

    for (int t = c0; t < c0 + 32; t++) {
        const float* hi = hbuf + (size_t)(t & 1) * 2 * 98304 + (size_t)dir * 98304;
        float* ho = hbuf + (size_t)(1 - (t & 1)) * 2 * 98304 + (size_t)dir * 98304;

        for (int ii = tid; ii < 3072; ii += 512) {
            int r2 = ii / 96, c2 = (ii - r2 * 96) * 4;
            *(f32x4*)&hrow[r2][c2] = *(const f32x4*)&hi[(size_t)(r0g + r2) * 384 + c2];
        }
        __syncthreads();

        float a0 = 0.f, a1 = 0.f, a2 = 0.f, a3 = 0.f;
        float b0 = 0.f, b1 = 0.f, b2 = 0.f, b3 = 0.f;
#pragma unroll 8
        for (int k = 0; k < 384; k++) {
            f32x4 wv = *(const f32x4*)(wpb + (size_t)k * 1536);
            float hA = hrow[rr][k];
            float hB = hrow[rr + 16][k];
            a0 += hA * wv[0]; a1 += hA * wv[1]; a2 += hA * wv[2]; a3 += hA * wv[3];
            b0 += hB * wv[0]; b1 += hB * wv[1]; b2 += hB * wv[2]; b3 += hB * wv[3];
        }

        auto finish = [&](int bg, float s0, float s1, float s2, float s3) {
            int len = slen[bg];
            int tsrc = dir ? (t < len ? len - 1 - t : t) : t;
            const float* gp = gch + (((size_t)bg << 5) + (t & 31)) * 1536;
            float gi = s0 + __builtin_nontemporal_load(gp + ug);
            float gf = s1 + __builtin_nontemporal_load(gp + 384 + ug);
            float gg2 = s2 + __builtin_nontemporal_load(gp + 768 + ug);
            float go = s3 + __builtin_nontemporal_load(gp + 1152 + ug);
            float si = 1.f / (1.f + __expf(-gi));
            float sf = 1.f / (1.f + __expf(-gf));
            float so = 1.f / (1.f + __expf(-go));
            float tg = tanhf(gg2);
            int ci = bg * 384 + ug;
            float cn = sf * cs[ci] + si * tg;
            float hn = so * tanhf(cn);
            cs[ci] = cn;
            ho[ci] = hn;
            int tpos = dir ? tsrc : t;
            __builtin_nontemporal_store(hn, &Hs[((size_t)bg * 96 + tpos) * 768 +
                                                dir * 384 + ug]);
        };
        finish(r0g + rr, a0, a1, a2, a3);
        finish(r0g + rr + 16, b0, b1, b2, b3);

        // group barrier: all 12 u-tile blocks of (r-tile, dir) finish step t
        __syncthreads();  // drains each thread's global stores (vmcnt 0) first
        if (tid == 0) {
            __threadfence();  // release: publish h/c writes device-wide
            __hip_atomic_fetch_add(gbar, 1u, __ATOMIC_RELEASE,
                                   __HIP_MEMORY_SCOPE_AGENT);
            unsigned tgt = 12u * (unsigned)(t - c0 + 1);
            while (__hip_atomic_load(gbar, __ATOMIC_ACQUIRE,
                                     __HIP_MEMORY_SCOPE_AGENT) < tgt)
                __builtin_amdgcn_s_sleep(2);
            __threadfence();  // acquire: invalidate stale cached h
        }
        __syncthreads();
    }
}

// ---------------------------------------------------------------- small kernels
__global__ void k_bias2(const float* a, const float* b, float* o, int n) {
    int i = blockIdx.x * 256 + threadIdx.x;
    if (i < n) o[i] = a[i] + b[i];
}

__global__ __launch_bounds__(256) void k_transp32(const float* __restrict__ src,
                                                  float* __restrict__ dst, int roff) {
    __shared__ float tile[32][33];
    int tx = threadIdx.x & 31, ty = threadIdx.x >> 5;
    int n0 = blockIdx.x * 32, k0 = blockIdx.y * 32;
#pragma unroll
    for (int r = ty; r < 32; r += 8)
        tile[r][tx] = src[(size_t)(roff + k0 + r) * 768 + n0 + tx];
    __syncthreads();
#pragma unroll
    for (int r = ty; r < 32; r += 8)
        dst[(size_t)(n0 + r) * 768 + k0 + tx] = tile[tx][r];
}

__global__ __launch_bounds__(256) void k_b2cat32(const float* __restrict__ W2,
                                                 float* __restrict__ dst) {
    __shared__ float tile[32][33];
    int tx = threadIdx.x & 31, ty = threadIdx.x >> 5;
    int n0 = blockIdx.x * 32, k0 = blockIdx.y * 32;
#pragma unroll
    for (int r = ty; r < 32; r += 8) {
        int k = k0 + r;
        float v = 0.f;
        if (k < 1586) {
            int sr = (k < 768) ? 768 + k : 769 + k;
            v = W2[(size_t)sr * 768 + n0 + tx];
        }
        tile[r][tx] = v;
    }
    __syncthreads();
#pragma unroll
    for (int r = ty; r < 32; r += 8)
        dst[(size_t)(n0 + r) * 1600 + k0 + tx] = tile[tx][r];
}

// alpha = e*mask / (sum + 1e-9); U[b,:] = sum_t alpha[t]*Hs[b,t,:]
__global__ __launch_bounds__(256) void k_alpha_u(const float* __restrict__ escoreP,
                                                 const float* __restrict__ Hs,
                                                 const int* __restrict__ slen,
                                                 float* __restrict__ U) {
    __shared__ float al[96];
    __shared__ float dsh;
    int b = blockIdx.x, tid = threadIdx.x;
    int len = slen[b];
    if (tid < 96) {
        const float* ep = escoreP + (size_t)(b * 96 + tid) * 6;
        float e = ep[0] + ep[1] + ep[2] + ep[3] + ep[4] + ep[5];
        al[tid] = (tid < len) ? e : 0.f;
    }
    __syncthreads();
    if (tid == 0) {
        float s = 0.f;
        for (int i = 0; i < 96; i++) s += al[i];
        dsh = 1.f / (s + 1e-9f);
    }
    __syncthreads();
    float dinv = dsh;
    for (int d = tid; d < 768; d += 256) {
        float acc = 0.f;
        const float* hp = Hs + (size_t)b * 96 * 768 + d;
        for (int tt = 0; tt < 96; tt++) acc += al[tt] * hp[(size_t)tt * 768];
        U[(size_t)b * 768 + d] = acc * dinv;
    }
}

__global__ void k_ucat(const float* __restrict__ U, const int* __restrict__ cau,
                       const int* __restrict__ emo, float* __restrict__ Ucat) {
    int i = blockIdx.x * 256 + threadIdx.x;
    if (i < 384 * 768) {
        int r = i / 768, d = i - r * 768;
        int src = (r < 256) ? cau[r] : emo[r - 256];
        Ucat[i] = U[(size_t)src * 768 + d];
    }
}

__global__ __launch_bounds__(256) void k_chunk_sc(const float* __restrict__ CuEf,
                                                  float* __restrict__ sc) {
    int m = blockIdx.x;
    int e = m >> 6, nk = m & 63;
    int tid = threadIdx.x, w = tid >> 6, lane = tid & 63;
    const float* Er = CuEf + (size_t)(256 + e) * 768;
    const float* Cr = CuEf + (size_t)(nk * 4 + w) * 768;
    float acc = 0.f;
    for (int q = lane; q < 768; q += 64) acc += Er[q] * Cr[q];
    for (int off = 32; off; off >>= 1) acc += __shfl_xor(acc, off);
    __shared__ float S[4];
    if (lane == 0) S[w] = acc;
    __syncthreads();
    if (tid == 0) {
        float mx = fmaxf(fmaxf(S[0], S[1]), fmaxf(S[2], S[3]));
        float e0 = expf(S[0] - mx), e1 = expf(S[1] - mx), e2 = expf(S[2] - mx),
              e3 = expf(S[3] - mx);
        float inv = 1.f / (e0 + e1 + e2 + e3);
        sc[4 * m] = e0 * inv; sc[4 * m + 1] = e1 * inv;
        sc[4 * m + 2] = e2 * inv; sc[4 * m + 3] = e3 * inv;
    }
}

__global__ void k_chunk_emb(const float* __restrict__ sc, const float* __restrict__ CuEf,
                            float* __restrict__ ce) {
    int i = blockIdx.x * 256 + threadIdx.x;
    if (i < 8192 * 768) {
        int m = i / 768, d = i - m * 768;
        int nk = m & 63;
        const float* base = CuEf + (size_t)(nk * 4) * 768 + d;
        ce[i] = sc[4 * m] * base[0] + sc[4 * m + 1] * base[768] +
                sc[4 * m + 2] * base[1536] + sc[4 * m + 3] * base[2304];
    }
}

__global__ __launch_bounds__(256) void k_nrm2(const float* __restrict__ ce,
                                              const float* __restrict__ CuEf,
                                              float* __restrict__ nrm2) {
    int m = blockIdx.x, tid = threadIdx.x;
    int e = m >> 6;
    const float* cr = ce + (size_t)m * 768;
    const float* er = CuEf + (size_t)(256 + e) * 768;
    float ss = 0.f;
    for (int d = tid; d < 768; d += 256) {
        float df = er[d] - cr[d];
        ss += df * df;
    }
    for (int off = 32; off; off >>= 1) ss += __shfl_xor(ss, off);
    __shared__ float red[4];
    if ((tid & 63) == 0) red[tid >> 6] = ss;
    __syncthreads();
    if (tid == 0) nrm2[m] = sqrtf(red[0] + red[1] + red[2] + red[3]);
}

__global__ __launch_bounds__(256) void k_nrm3(const float* __restrict__ CuEf,
                                              float* __restrict__ nrm3) {
    int m = blockIdx.x, tid = threadIdx.x;
    int e = m >> 8, j = m & 255;
    const float* cu = CuEf + (size_t)j * 768;
    const float* er = CuEf + (size_t)(256 + e) * 768;
    float ss = 0.f;
    for (int d = tid; d < 768; d += 256) {
        float df = er[d] - cu[d];
        ss += df * df;
    }
    for (int off = 32; off; off >>= 1) ss += __shfl_xor(ss, off);
    __shared__ float red[4];
    if ((tid & 63) == 0) red[tid >> 6] = ss;
    __syncthreads();
    if (tid == 0) nrm3[m] = sqrtf(red[0] + red[1] + red[2] + red[3]);
}

__global__ void k_bv3_dis(float* __restrict__ Bv3, const float* __restrict__ dis,
                          const float* __restrict__ W3, const float* __restrict__ b3) {
    int i = blockIdx.x * 256 + threadIdx.x;
    if (i < 256 * 768) {
        int j = i / 768, n = i - j * 768;
        float s = Bv3[i] + b3[n];
        const float* dr = dis + j * 50;
#pragma unroll 10
        for (int q = 0; q < 50; q++) s += dr[q] * W3[(size_t)(2305 + q) * 768 + n];
        Bv3[i] = s;
    }
}

template <int GROUP>
__global__ __launch_bounds__(256) void k_bnstats(const float* __restrict__ z,
                                                 float* __restrict__ mean,
                                                 float* __restrict__ rstd) {
    int idx = blockIdx.x * 256 + threadIdx.x;
    if (idx >= 128 * 768) return;
    int e = idx / 768, n = idx - e * 768;
    const float* p = z + (size_t)e * GROUP * 768 + n;
    float s = 0.f;
    for (int k = 0; k < GROUP; k++) s += p[(size_t)k * 768];
    float mu = s * (1.f / GROUP);
    float q = 0.f;
    for (int k = 0; k < GROUP; k++) {
        float d = p[(size_t)k * 768] - mu;
        q += d * d;
    }
    mean[idx] = mu;
    rstd[idx] = rsqrtf(q * (1.f / GROUP) + 1e-5f);
}

template <int GROUP>
__global__ __launch_bounds__(256) void k_bn_head(const float* __restrict__ z,
                                                 const float* __restrict__ mean,
                                                 const float* __restrict__ rstd,
                                                 const float* __restrict__ W,
                                                 const float* __restrict__ bb,
                                                 float* __restrict__ outp,
                                                 float* __restrict__ feat) {
    int m = blockIdx.x;
    int e = m / GROUP;
    int tid = threadIdx.x;
    float a0 = 0.f, a1 = 0.f;
    const float* zr = z + (size_t)m * 768;
    const float* mr = mean + (size_t)e * 768;
    const float* rr = rstd + (size_t)e * 768;
    for (int n = tid; n < 768; n += 256) {
        float h = (zr[n] - mr[n]) * rr[n];
        h = h > 0.f ? h : 0.01f * h;
        a0 += h * W[2 * n];
        a1 += h * W[2 * n + 1];
    }
    for (int off = 32; off; off >>= 1) {
        a0 += __shfl_xor(a0, off);
        a1 += __shfl_xor(a1, off);
    }
    __shared__ float s0[4], s1v[4];
    int w = tid >> 6;
    if ((tid & 63) == 0) { s0[w] = a0; s1v[w] = a1; }
    __syncthreads();
    if (tid == 0) {
        float l0 = s0[0] + s0[1] + s0[2] + s0[3] + bb[0];
        float l1 = s1v[0] + s1v[1] + s1v[2] + s1v[3] + bb[1];
        float mx = fmaxf(l0, l1);
        float ls = mx + logf(expf(l0 - mx) + expf(l1 - mx));
        outp[2 * m] = l0 - ls;
        outp[2 * m + 1] = l1 - ls;
        if (feat) feat[m] = (l1 > l0) ? 1.f : 0.f;
    }
}

__global__ void k_label(const int* __restrict__ l3, float* __restrict__ out) {
    int e = blockIdx.x, c = threadIdx.x;
    int a = l3[e * 3], b = l3[e * 3 + 1], d = l3[e * 3 + 2];
    out[e * 256 + c] = (a == c || b == c || d == c) ? 1.f : 0.f;
}

// ---------------------------------------------------------------- host
extern "C" void kernel_launch(void* const* d_in, const int* in_sizes, int n_in,
                              void* d_out, int out_size, void* d_ws, size_t ws_size,
                              hipStream_t stream) {
    (void)in_sizes; (void)n_in; (void)out_size; (void)ws_size;
    const float* word = (const float*)d_in[0];
    const float* pos = (const float*)d_in[1];
    const float* dis = (const float*)d_in[2];
    const float* WihF = (const float*)d_in[3];
    const float* WhhF = (const float*)d_in[4];
    const float* bihF = (const float*)d_in[5];
    const float* bhhF = (const float*)d_in[6];
    const float* WihB = (const float*)d_in[7];
    const float* WhhB = (const float*)d_in[8];
    const float* bihB = (const float*)d_in[9];
    const float* bhhB = (const float*)d_in[10];
    const float* s1W = (const float*)d_in[11];
    const float* s1b = (const float*)d_in[12];
    const float* s2W = (const float*)d_in[13];
    const float* repW = (const float*)d_in[14];
    const float* repb = (const float*)d_in[15];
    const float* W2W = (const float*)d_in[16];
    const float* W2b = (const float*)d_in[17];
    const float* WoW = (const float*)d_in[18];
    const float* Wob = (const float*)d_in[19];
    const float* W3W = (const float*)d_in[20];
    const float* W3b = (const float*)d_in[21];
    const float* clsW = (const float*)d_in[22];
    const float* clsb = (const float*)d_in[23];
    const int* slen = (const int*)d_in[24];
    const int* emo = (const int*)d_in[25];
    const int* cau = (const int*)d_in[26];
    const int* lab3 = (const int*)d_in[27];
    float* out = (float*)d_out;

    char* ws = (char*)d_ws;
    size_t off = 0;
    auto alloc = [&](size_t b) -> char* {
        char* p = ws + off;
        off += (b + 255) & ~(size_t)255;
        return p;
    };
    float* biasF = (float*)alloc(1536 * 4);
    float* biasB = (float*)alloc(1536 * 4);
    float* wpF = (float*)alloc((size_t)384 * 1536 * 4);
    float* wpB = (float*)alloc((size_t)384 * 1536 * 4);
    float* s1T = (float*)alloc((size_t)768 * 768 * 4);
    float* repT = (float*)alloc((size_t)768 * 768 * 4);
    float* W2aT = (float*)alloc((size_t)768 * 768 * 4);
    float* W3aT = (float*)alloc((size_t)768 * 768 * 4);
    float* W3bT = (float*)alloc((size_t)768 * 768 * 4);
    float* W3dT = (float*)alloc((size_t)768 * 768 * 4);
    float* B2cat = (float*)alloc((size_t)768 * 1600 * 4);
    float* hbuf = (float*)alloc((size_t)4 * 98304 * 4);  // [pp][dir][256*384]
    float* cbuf = (float*)alloc((size_t)2 * 98304 * 4);
    float* Hsf = (float*)alloc((size_t)24576 * 768 * 4);  // 75.5 MB
    float* escoreP = (float*)alloc((size_t)24576 * 6 * 4);
    float* Uf = (float*)alloc((size_t)256 * 768 * 4);
    float* UcatF = (float*)alloc((size_t)384 * 768 * 4);
    float* CuEf = (float*)alloc((size_t)384 * 768 * 4);  // rows 0:256 Cu, 256:384 E
    float* scF = (float*)alloc((size_t)8192 * 4 * 4);
    float* nrm2F = (float*)alloc(8192 * 4);
    float* nrm3F = (float*)alloc(32768 * 4);
    float* E2F = (float*)alloc((size_t)128 * 768 * 4);
    float* E3F = (float*)alloc((size_t)128 * 768 * 4);
    float* Bv3F = (float*)alloc((size_t)256 * 768 * 4);
    float* mean2 = (float*)alloc((size_t)128 * 768 * 4);
    float* rstd2 = (float*)alloc((size_t)128 * 768 * 4);
    float* mean3 = (float*)alloc((size_t)128 * 768 * 4);
    float* rstd3 = (float*)alloc((size_t)128 * 768 * 4);
    float* outfeatF = (float*)alloc(8192 * 4);
    unsigned* barU = (unsigned*)alloc(16 * 256);  // 16 groups x 256 B
    char* BIG = alloc((size_t)103 * 1024 * 1024);

    float* gchF = (float*)BIG;                      // [8192,1536] f32 = 50.33 MB
    float* gchB = (float*)(BIG + (size_t)50331648);
    float* ceF = (float*)BIG;                       // [8192,768] f32 = 25.17 MB
    float* z2F = (float*)(BIG + (size_t)25165824);  // [8192,768] f32
    float* z3F = (float*)BIG;                       // [32768,768] f32 = 100.7 MB

    // ---- init
    hipMemsetAsync(hbuf, 0, (size_t)4 * 98304 * 4 + (size_t)2 * 98304 * 4, stream);

    // ---- weight prep
    k_bias2<<<6, 256, 0, stream>>>(bihF, bhhF, biasF, 1536);
    k_bias2<<<6, 256, 0, stream>>>(bihB, bhhB, biasB, 1536);
    k_wpack<<<2304, 256, 0, stream>>>(WhhF, wpF);
    k_wpack<<<2304, 256, 0, stream>>>(WhhB, wpB);
    k_transp32<<<dim3(24, 24), 256, 0, stream>>>(s1W, s1T, 0);
    k_transp32<<<dim3(24, 24), 256, 0, stream>>>(repW, repT, 0);
    k_transp32<<<dim3(24, 24), 256, 0, stream>>>(W2W, W2aT, 0);
    k_transp32<<<dim3(24, 24), 256, 0, stream>>>(W3W, W3aT, 0);
    k_transp32<<<dim3(24, 24), 256, 0, stream>>>(W3W, W3bT, 768);
    k_transp32<<<dim3(24, 24), 256, 0, stream>>>(W3W, W3dT, 1537);
    k_b2cat32<<<dim3(24, 50), 256, 0, stream>>>(W2W, B2cat);

    // ---- LSTM: 3 chunks {2 gate GEMMs + 1 persistent 32-step kernel}
    for (int c = 0; c < 3; c++) {
        {
            G32 g{};
            g.A = word; g.B = WihF; g.bias = biasF; g.out = gchF; g.slen = slen;
            g.M = 8192; g.N = 1536; g.K = 768; g.lda = 768; g.ldb = 768; g.ldc = 1536;
            g.c0 = c * 32;
            k_gemm32<1, 0><<<dim3(12, 64), 512, 0, stream>>>(g);
            g.B = WihB; g.bias = biasB; g.out = gchB;
            k_gemm32<3, 0><<<dim3(12, 64), 512, 0, stream>>>(g);
        }
        hipMemsetAsync(barU, 0, 16 * 256, stream);
        k_lstm_chunk<<<dim3(12, 8, 2), 512, 0, stream>>>(gchF, gchB, wpF, wpB,
                                                         hbuf, cbuf, Hsf, slen,
                                                         barU, c * 32);
    }

    // ---- attention scores (fixed-order partials, no atomics)
    {
        G32 g{};
        g.A = Hsf; g.B = s1T; g.bias = s1b; g.s2v = s2W; g.escoreP = escoreP;
        g.M = 24576; g.N = 768; g.K = 768; g.lda = 768; g.ldb = 768; g.ldc = 768;
        k_gemm32<0, 3><<<dim3(6, 192), 512, 0, stream>>>(g);
    }
    k_alpha_u<<<256, 256, 0, stream>>>(escoreP, Hsf, slen, Uf);
    k_ucat<<<(384 * 768 + 255) / 256, 256, 0, stream>>>(Uf, cau, emo, UcatF);

    // ---- Cu / E = lrelu(U[idx] @ rep + b)
    {
        G32 g{};
        g.A = UcatF; g.B = repT; g.bias = repb; g.out = CuEf;
        g.M = 384; g.N = 768; g.K = 768; g.lda = 768; g.ldb = 768; g.ldc = 768;
        k_gemm32<0, 2><<<dim3(6, 3), 512, 0, stream>>>(g);
    }

    // ---- chunk attention
    k_chunk_sc<<<8192, 256, 0, stream>>>(CuEf, scF);
    k_chunk_emb<<<(8192 * 768 + 255) / 256, 256, 0, stream>>>(scF, CuEf, ceF);

    // ---- phase 2
    k_nrm2<<<8192, 256, 0, stream>>>(ceF, CuEf, nrm2F);
    {
        G32 g{};
        g.A = CuEf + (size_t)256 * 768; g.B = W2aT; g.out = E2F;
        g.M = 128; g.N = 768; g.K = 768; g.lda = 768; g.ldb = 768; g.ldc = 768;
        k_gemm32<0, 0><<<dim3(6, 1), 512, 0, stream>>>(g);
    }
    {
        G32 g{};
        g.B = B2cat; g.out = z2F; g.bias = W2b;
        g.addE = E2F; g.nrm = nrm2F; g.wn = W2W + (size_t)1536 * 768;
        g.ce = ceF; g.CuEf = CuEf; g.pos = pos;
        g.M = 8192; g.N = 768; g.K = 1600; g.ldb = 1600; g.ldc = 768;
        k_gemm32<4, 4><<<dim3(6, 64), 512, 0, stream>>>(g);
    }
    k_bnstats<64><<<384, 256, 0, stream>>>(z2F, mean2, rstd2);
    k_bn_head<64><<<8192, 256, 0, stream>>>(z2F, mean2, rstd2, WoW, Wob, out, outfeatF);

    // ---- phase 3
    k_nrm3<<<32768, 256, 0, stream>>>(CuEf, nrm3F);
    {
        G32 g{};
        g.A = CuEf; g.B = W3bT; g.out = Bv3F;
        g.M = 256; g.N = 768; g.K = 768; g.lda = 768; g.ldb = 768; g.ldc = 768;
        k_gemm32<0, 0><<<dim3(6, 2), 512, 0, stream>>>(g);
    }
    k_bv3_dis<<<(256 * 768 + 255) / 256, 256, 0, stream>>>(Bv3F, dis, W3W, W3b);
    {
        G32 g{};
        g.A = CuEf + (size_t)256 * 768; g.B = W3aT; g.out = E3F;
        g.M = 128; g.N = 768; g.K = 768; g.lda = 768; g.ldb = 768; g.ldc = 768;
        k_gemm32<0, 0><<<dim3(6, 1), 512, 0, stream>>>(g);
    }
    {
        G32 g{};
        g.B = W3dT; g.out = z3F;
        g.addE = E3F; g.addB = Bv3F; g.nrm = nrm3F; g.wn = W3W + (size_t)1536 * 768;
        g.feat = outfeatF; g.wx = W3W + (size_t)2355 * 768;
        g.CuEf = CuEf;
        g.M = 32768; g.N = 768; g.K = 768; g.ldb = 768; g.ldc = 768;
        k_gemm32<2, 5><<<dim3(6, 256), 512, 0, stream>>>(g);
    }
    k_bnstats<256><<<384, 256, 0, stream>>>(z3F, mean3, rstd3);
    k_bn_head<256><<<32768, 256, 0, stream>>>(z3F, mean3, rstd3, clsW, clsb, out + 16384, nullptr);

    // ---- L
    k_label<<<128, 256, 0, stream>>>(lab3, out + 81920);
}

// Round 10
// 5681.810 us; speedup vs baseline: 1.3831x; 1.3831x over previous
//
#include <hip/hip_runtime.h>
#include <cstdint>
#include <cstddef>

// ECPEC pipeline for MI355X (gfx950) — f32 everywhere (upstream precision is
// load-bearing: the alpha-denominator amplifies rounding ~1e6x; bf16 fails).
// R10: LSTM re-partitioned by ROWS (rows are recurrence-independent!) —
// 128 blocks x (4 rows, 1 dir, all 384 units), 32 steps per launch, h in LDS,
// c in registers, NO inter-block sync. Whh streamed from L2 (dir = blockIdx
// parity -> per-XCD L2 affinity). Math bitwise-identical to R7/R9.

#define DEV __device__ __forceinline__
typedef float f32x4 __attribute__((ext_vector_type(4)));

// ---------------------------------------------------------------- f32 GEMM
// C[M,N] = A[M,K] @ B[N,K]^T ; tile 128x128, BK=32, 512 threads, 4x8 acc/thread.
// AMODE: 0 plain A ; 1 gate-gather fwd ; 3 gate-gather rev ; 2 A=E[e]*Cu[j] ;
//        4 phase-2 fold (ce | E*ce | pos | 0)
// EPI:   0 acc(+bias?) ; 2 lrelu(acc+bias) ; 3 score partials ; 4 phase-2 ; 5 phase-3
struct G32 {
    const float* A;
    const float* B;
    float* out;
    const float* bias;
    const float* s2v;
    float* escoreP;      // [M][6] partials (EPI 3)
    const float* addE;
    const float* addB;
    const float* nrm;
    const float* wn;
    const float* feat;
    const float* wx;
    const float* ce;
    const float* CuEf;
    const float* pos;
    const int* slen;
    int M, N, K, lda, ldb, ldc, c0;
};

template <int AMODE, int EPI>
__global__ __launch_bounds__(512) void k_gemm32(G32 p) {
    __shared__ __align__(16) float As[32][132];  // [kk][m]
    __shared__ __align__(16) float Bs[32][132];  // [kk][n]
    const int tid = threadIdx.x;
    const int tx = tid & 15, ty = tid >> 4;      // ty 0..31
    const int m0 = blockIdx.y * 128, n0 = blockIdx.x * 128;
    float acc[4][8] = {};
    const int ra = tid >> 2;          // 0..127
    const int ka = (tid & 3) * 8;     // 0,8,16,24
    const int gmA = m0 + ra;

    const float* arow = nullptr;
    const float* er = nullptr;
    const float* cr = nullptr;
    const float* prow = nullptr;
    if constexpr (AMODE == 0) {
        arow = p.A + (size_t)gmA * p.lda;
    } else if constexpr (AMODE == 1 || AMODE == 3) {
        int b = gmA >> 5, t = p.c0 + (gmA & 31);
        if constexpr (AMODE == 3) {
            int len = p.slen[b];
            t = (t < len) ? len - 1 - t : t;
        }
        arow = p.A + ((size_t)b * 96 + t) * 768;
    } else if constexpr (AMODE == 2) {
        int e = gmA >> 8, j = gmA & 255;
        er = p.CuEf + (size_t)(256 + e) * 768;
        cr = p.CuEf + (size_t)j * 768;
    } else if constexpr (AMODE == 4) {
        er = p.CuEf + (size_t)(256 + (gmA >> 6)) * 768;
        cr = p.ce + (size_t)gmA * 768;
        prow = p.pos + (size_t)gmA * 50;
    }
    const float* brow = p.B + (size_t)(n0 + ra) * p.ldb;

    auto load_tile = [&](int kt, float* av, float* bv) {
        if constexpr (AMODE == 0 || AMODE == 1 || AMODE == 3) {
            const float* ap = arow + kt + ka;
#pragma unroll
            for (int q = 0; q < 8; q++) av[q] = ap[q];
        } else if constexpr (AMODE == 2) {
#pragma unroll
            for (int q = 0; q < 8; q++) av[q] = er[kt + ka + q] * cr[kt + ka + q];
        } else {
#pragma unroll
            for (int q = 0; q < 8; q++) {
                int k = kt + ka + q;
                float x;
                if (k < 768) x = cr[k];
                else if (k < 1536) x = er[k - 768] * cr[k - 768];
                else if (k < 1586) x = prow[k - 1536];
                else x = 0.f;
                av[q] = x;
            }
        }
        const float* bp = brow + kt + ka;
#pragma unroll
        for (int q = 0; q < 8; q++) bv[q] = bp[q];
    };

    const int nt = p.K / 32;
    float av[8], bv[8];
    load_tile(0, av, bv);
    for (int t = 0; t < nt; t++) {
        __syncthreads();  // previous compute done reading LDS
#pragma unroll
        for (int q = 0; q < 8; q++) {
            As[ka + q][ra] = av[q];
            Bs[ka + q][ra] = bv[q];
        }
        __syncthreads();
        if (t + 1 < nt) load_tile((t + 1) * 32, av, bv);  // overlap with compute
#pragma unroll
        for (int kk = 0; kk < 32; kk++) {
            float a[4], b[8];
            *(f32x4*)a = *(const f32x4*)&As[kk][ty * 4];
            *(f32x4*)b = *(const f32x4*)&Bs[kk][tx * 4];
            *(f32x4*)(b + 4) = *(const f32x4*)&Bs[kk][64 + tx * 4];
#pragma unroll
            for (int i = 0; i < 4; i++)
#pragma unroll
                for (int j = 0; j < 8; j++) acc[i][j] += a[i] * b[j];
        }
    }

    if constexpr (EPI == 3) {
#pragma unroll
        for (int i = 0; i < 4; i++) {
            float s = 0.f;
#pragma unroll
            for (int j = 0; j < 8; j++) {
                int n = n0 + ((j < 4) ? tx * 4 + j : 64 + tx * 4 + (j - 4));
                float x = acc[i][j] + p.bias[n];
                x = x > 0.f ? x : 0.01f * x;
                s += x * p.s2v[n];
            }
            s += __shfl_xor(s, 1);
            s += __shfl_xor(s, 2);
            s += __shfl_xor(s, 4);
            s += __shfl_xor(s, 8);
            if (tx == 0) {
                int m = m0 + ty * 4 + i;
                p.escoreP[(size_t)m * 6 + blockIdx.x] = s;
            }
        }
    } else {
#pragma unroll
        for (int i = 0; i < 4; i++)
#pragma unroll
            for (int j = 0; j < 8; j++) {
                int m = m0 + ty * 4 + i;
                int n = n0 + ((j < 4) ? tx * 4 + j : 64 + tx * 4 + (j - 4));
                float x = acc[i][j];
                if constexpr (EPI == 0) {
                    if (p.bias) x += p.bias[n];
                } else if constexpr (EPI == 2) {
                    x += p.bias[n];
                    x = x > 0.f ? x : 0.01f * x;
                } else if constexpr (EPI == 4) {
                    int e = m >> 6;
                    x += p.addE[(size_t)e * 768 + n] + p.nrm[m] * p.wn[n] + p.bias[n];
                } else if constexpr (EPI == 5) {
                    int e = m >> 8, jj = m & 255;
                    float ex = p.feat[e * 64 + (jj >> 2)];
                    x += p.addE[(size_t)e * 768 + n] + p.addB[(size_t)jj * 768 + n] +
                         p.nrm[m] * p.wn[n] + ex * p.wx[n];
                }
                p.out[(size_t)m * p.ldc + n] = x;
            }
    }
}

// ---------------------------------------------------------------- Whh pack
// Wpack[k][u*4+g] = Whh[g*384+u][k]  (one coalesced f32x4 per thread per k)
__global__ void k_wpack(const float* __restrict__ whh, float* __restrict__ wp) {
    int idx = blockIdx.x * 256 + threadIdx.x;
    if (idx < 384 * 1536) {
        int k = idx / 1536, rem = idx - k * 1536;
        int u = rem >> 2, g = rem & 3;
        wp[idx] = whh[(size_t)(g * 384 + u) * 384 + k];
    }
}

// ---------------------------------------------------------------- LSTM rows
// Row-partitioned, sync-free: block = 384 threads (thread = unit u), owns
// 4 rows of ONE direction, runs 32 steps with h in LDS and c in registers.
// Rows are recurrence-independent -> no inter-block sync. dir = blockIdx&1
// (XCD round-robin makes each XCD L2 cache only one dir's 2.4 MB wp).
// Per-(row,gate) accumulation: k ascending, identical to prior kernels.
__global__ __launch_bounds__(384) void k_lstm_rows(
    const float* __restrict__ gchF, const float* __restrict__ gchB,
    const float* __restrict__ wpF, const float* __restrict__ wpB,
    float* __restrict__ hbuf, float* __restrict__ cbuf, float* __restrict__ Hs,
    const int* __restrict__ slen, int c0) {
    __shared__ __align__(16) float hlds[4][384];  // 6 KB
    const int tid = threadIdx.x;
    const int dir = blockIdx.x & 1;
    const int r0 = (blockIdx.x >> 1) * 4;  // first row of this block
    const float* gch = dir ? gchB : gchF;
    const float* wp = dir ? wpB : wpF;
    float* hb = hbuf + (size_t)dir * 98304;
    float* cb = cbuf + (size_t)dir * 98304;
    const int u = tid;

    // load h (LDS) and c (registers) for this block's 4 rows
    {
        int r = tid / 96, c4 = (tid - r * 96) * 4;
        *(f32x4*)&hlds[r][c4] = *(const f32x4*)&hb[(size_t)(r0 + r) * 384 + c4];
    }
    float c_[4];
    int len_[4];
#pragma unroll
    for (int r = 0; r < 4; r++) {
        c_[r] = cb[(size_t)(r0 + r) * 384 + u];
        len_[r] = slen[r0 + r];
    }
    __syncthreads();

    const float* wpb = wp + (size_t)u * 4;
    for (int t = c0; t < c0 + 32; t++) {
        float acc[4][4] = {};  // [row][gate]
#pragma unroll 4
        for (int k = 0; k < 384; k++) {
            f32x4 wv = *(const f32x4*)(wpb + (size_t)k * 1536);
            float h0 = hlds[0][k], h1 = hlds[1][k];
            float h2 = hlds[2][k], h3 = hlds[3][k];
#pragma unroll
            for (int g = 0; g < 4; g++) {
                acc[0][g] += h0 * wv[g];
                acc[1][g] += h1 * wv[g];
                acc[2][g] += h2 * wv[g];
                acc[3][g] += h3 * wv[g];
            }
        }
        __syncthreads();  // all reads of hlds for step t complete
#pragma unroll
        for (int r = 0; r < 4; r++) {
            int bg = r0 + r;
            int len = len_[r];
            int tsrc = dir ? (t < len ? len - 1 - t : t) : t;
            const float* gp = gch + (((size_t)bg << 5) + (t & 31)) * 1536;
            float gi = acc[r][0] + gp[u];
            float gf = acc[r][1] + gp[384 + u];
            float gg2 = acc[r][2] + gp[768 + u];
            float go = acc[r][3] + gp[1152 + u];
            float si = 1.f / (1.f + __expf(-gi));
            float sf = 1.f / (1.f + __expf(-gf));
            float so = 1.f / (1.f + __expf(-go));
            float tg = tanhf(gg2);
            float cn = sf * c_[r] + si * tg;
            float hn = so * tanhf(cn);
            c_[r] = cn;
            hlds[r][u] = hn;
            int tpos = dir ? tsrc : t;
            Hs[((size_t)bg * 96 + tpos) * 768 + dir * 384 + u] = hn;
        }
        __syncthreads();  // h update visible before next step's reads
    }

    // persist h, c for the next chunk
    {
        int r = tid / 96, c4 = (tid - r * 96) * 4;
        *(f32x4*)&hb[(size_t)(r0 + r) * 384 + c4] = *(const f32x4*)&hlds[r][c4];
    }
#pragma unroll
    for (int r = 0; r < 4; r++) cb[(size_t)(r0 + r) * 384 + u] = c_[r];
}

// ---------------------------------------------------------------- small kernels
__global__ void k_bias2(const float* a, const float* b, float* o, int n) {
    int i = blockIdx.x * 256 + threadIdx.x;
    if (i < n) o[i] = a[i] + b[i];
}

__global__ __launch_bounds__(256) void k_transp32(const float* __restrict__ src,
                                                  float* __restrict__ dst, int roff) {
    __shared__ float tile[32][33];
    int tx = threadIdx.x & 31, ty = threadIdx.x >> 5;
    int n0 = blockIdx.x * 32, k0 = blockIdx.y * 32;
#pragma unroll
    for (int r = ty; r < 32; r += 8)
        tile[r][tx] = src[(size_t)(roff + k0 + r) * 768 + n0 + tx];
    __syncthreads();
#pragma unroll
    for (int r = ty; r < 32; r += 8)
        dst[(size_t)(n0 + r) * 768 + k0 + tx] = tile[tx][r];
}

__global__ __launch_bounds__(256) void k_b2cat32(const float* __restrict__ W2,
                                                 float* __restrict__ dst) {
    __shared__ float tile[32][33];
    int tx = threadIdx.x & 31, ty = threadIdx.x >> 5;
    int n0 = blockIdx.x * 32, k0 = blockIdx.y * 32;
#pragma unroll
    for (int r = ty; r < 32; r += 8) {
        int k = k0 + r;
        float v = 0.f;
        if (k < 1586) {
            int sr = (k < 768) ? 768 + k : 769 + k;
            v = W2[(size_t)sr * 768 + n0 + tx];
        }
        tile[r][tx] = v;
    }
    __syncthreads();
#pragma unroll
    for (int r = ty; r < 32; r += 8)
        dst[(size_t)(n0 + r) * 1600 + k0 + tx] = tile[tx][r];
}

// alpha = e*mask / (sum + 1e-9); U[b,:] = sum_t alpha[t]*Hs[b,t,:]
__global__ __launch_bounds__(256) void k_alpha_u(const float* __restrict__ escoreP,
                                                 const float* __restrict__ Hs,
                                                 const int* __restrict__ slen,
                                                 float* __restrict__ U) {
    __shared__ float al[96];
    __shared__ float dsh;
    int b = blockIdx.x, tid = threadIdx.x;
    int len = slen[b];
    if (tid < 96) {
        const float* ep = escoreP + (size_t)(b * 96 + tid) * 6;
        float e = ep[0] + ep[1] + ep[2] + ep[3] + ep[4] + ep[5];
        al[tid] = (tid < len) ? e : 0.f;
    }
    __syncthreads();
    if (tid == 0) {
        float s = 0.f;
        for (int i = 0; i < 96; i++) s += al[i];
        dsh = 1.f / (s + 1e-9f);
    }
    __syncthreads();
    float dinv = dsh;
    for (int d = tid; d < 768; d += 256) {
        float acc = 0.f;
        const float* hp = Hs + (size_t)b * 96 * 768 + d;
        for (int tt = 0; tt < 96; tt++) acc += al[tt] * hp[(size_t)tt * 768];
        U[(size_t)b * 768 + d] = acc * dinv;
    }
}

__global__ void k_ucat(const float* __restrict__ U, const int* __restrict__ cau,
                       const int* __restrict__ emo, float* __restrict__ Ucat) {
    int i = blockIdx.x * 256 + threadIdx.x;
    if (i < 384 * 768) {
        int r = i / 768, d = i - r * 768;
        int src = (r < 256) ? cau[r] : emo[r - 256];
        Ucat[i] = U[(size_t)src * 768 + d];
    }
}

__global__ __launch_bounds__(256) void k_chunk_sc(const float* __restrict__ CuEf,
                                                  float* __restrict__ sc) {
    int m = blockIdx.x;
    int e = m >> 6, nk = m & 63;
    int tid = threadIdx.x, w = tid >> 6, lane = tid & 63;
    const float* Er = CuEf + (size_t)(256 + e) * 768;
    const float* Cr = CuEf + (size_t)(nk * 4 + w) * 768;
    float acc = 0.f;
    for (int q = lane; q < 768; q += 64) acc += Er[q] * Cr[q];
    for (int off = 32; off; off >>= 1) acc += __shfl_xor(acc, off);
    __shared__ float S[4];
    if (lane == 0) S[w] = acc;
    __syncthreads();
    if (tid == 0) {
        float mx = fmaxf(fmaxf(S[0], S[1]), fmaxf(S[2], S[3]));
        float e0 = expf(S[0] - mx), e1 = expf(S[1] - mx), e2 = expf(S[2] - mx),
              e3 = expf(S[3] - mx);
        float inv = 1.f / (e0 + e1 + e2 + e3);
        sc[4 * m] = e0 * inv; sc[4 * m + 1] = e1 * inv;
        sc[4 * m + 2] = e2 * inv; sc[4 * m + 3] = e3 * inv;
    }
}

__global__ void k_chunk_emb(const float* __restrict__ sc, const float* __restrict__ CuEf,
                            float* __restrict__ ce) {
    int i = blockIdx.x * 256 + threadIdx.x;
    if (i < 8192 * 768) {
        int m = i / 768, d = i - m * 768;
        int nk = m & 63;
        const float* base = CuEf + (size_t)(nk * 4) * 768 + d;
        ce[i] = sc[4 * m] * base[0] + sc[4 * m + 1] * base[768] +
                sc[4 * m + 2] * base[1536] + sc[4 * m + 3] * base[2304];
    }
}

__global__ __launch_bounds__(256) void k_nrm2(const float* __restrict__ ce,
                                              const float* __restrict__ CuEf,
                                              float* __restrict__ nrm2) {
    int m = blockIdx.x, tid = threadIdx.x;
    int e = m >> 6;
    const float* cr = ce + (size_t)m * 768;
    const float* er = CuEf + (size_t)(256 + e) * 768;
    float ss = 0.f;
    for (int d = tid; d < 768; d += 256) {
        float df = er[d] - cr[d];
        ss += df * df;
    }
    for (int off = 32; off; off >>= 1) ss += __shfl_xor(ss, off);
    __shared__ float red[4];
    if ((tid & 63) == 0) red[tid >> 6] = ss;
    __syncthreads();
    if (tid == 0) nrm2[m] = sqrtf(red[0] + red[1] + red[2] + red[3]);
}

__global__ __launch_bounds__(256) void k_nrm3(const float* __restrict__ CuEf,
                                              float* __restrict__ nrm3) {
    int m = blockIdx.x, tid = threadIdx.x;
    int e = m >> 8, j = m & 255;
    const float* cu = CuEf + (size_t)j * 768;
    const float* er = CuEf + (size_t)(256 + e) * 768;
    float ss = 0.f;
    for (int d = tid; d < 768; d += 256) {
        float df = er[d] - cu[d];
        ss += df * df;
    }
    for (int off = 32; off; off >>= 1) ss += __shfl_xor(ss, off);
    __shared__ float red[4];
    if ((tid & 63) == 0) red[tid >> 6] = ss;
    __syncthreads();
    if (tid == 0) nrm3[m] = sqrtf(red[0] + red[1] + red[2] + red[3]);
}

__global__ void k_bv3_dis(float* __restrict__ Bv3, const float* __restrict__ dis,
                          const float* __restrict__ W3, const float* __restrict__ b3) {
    int i = blockIdx.x * 256 + threadIdx.x;
    if (i < 256 * 768) {
        int j = i / 768, n = i - j * 768;
        float s = Bv3[i] + b3[n];
        const float* dr = dis + j * 50;
#pragma unroll 10
        for (int q = 0; q < 50; q++) s += dr[q] * W3[(size_t)(2305 + q) * 768 + n];
        Bv3[i] = s;
    }
}

template <int GROUP>
__global__ __launch_bounds__(256) void k_bnstats(const float* __restrict__ z,
                                                 float* __restrict__ mean,
                                                 float* __restrict__ rstd) {
    int idx = blockIdx.x * 256 + threadIdx.x;
    if (idx >= 128 * 768) return;
    int e = idx / 768, n = idx - e * 768;
    const float* p = z + (size_t)e * GROUP * 768 + n;
    float s = 0.f;
    for (int k = 0; k < GROUP; k++) s += p[(size_t)k * 768];
    float mu = s * (1.f / GROUP);
    float q = 0.f;
    for (int k = 0; k < GROUP; k++) {
        float d = p[(size_t)k * 768] - mu;
        q += d * d;
    }
    mean[idx] = mu;
    rstd[idx] = rsqrtf(q * (1.f / GROUP) + 1e-5f);
}

template <int GROUP>
__global__ __launch_bounds__(256) void k_bn_head(const float* __restrict__ z,
                                                 const float* __restrict__ mean,
                                                 const float* __restrict__ rstd,
                                                 const float* __restrict__ W,
                                                 const float* __restrict__ bb,
                                                 float* __restrict__ outp,
                                                 float* __restrict__ feat) {
    int m = blockIdx.x;
    int e = m / GROUP;
    int tid = threadIdx.x;
    float a0 = 0.f, a1 = 0.f;
    const float* zr = z + (size_t)m * 768;
    const float* mr = mean + (size_t)e * 768;
    const float* rr = rstd + (size_t)e * 768;
    for (int n = tid; n < 768; n += 256) {
        float h = (zr[n] - mr[n]) * rr[n];
        h = h > 0.f ? h : 0.01f * h;
        a0 += h * W[2 * n];
        a1 += h * W[2 * n + 1];
    }
    for (int off = 32; off; off >>= 1) {
        a0 += __shfl_xor(a0, off);
        a1 += __shfl_xor(a1, off);
    }
    __shared__ float s0[4], s1v[4];
    int w = tid >> 6;
    if ((tid & 63) == 0) { s0[w] = a0; s1v[w] = a1; }
    __syncthreads();
    if (tid == 0) {
        float l0 = s0[0] + s0[1] + s0[2] + s0[3] + bb[0];
        float l1 = s1v[0] + s1v[1] + s1v[2] + s1v[3] + bb[1];
        float mx = fmaxf(l0, l1);
        float ls = mx + logf(expf(l0 - mx) + expf(l1 - mx));
        outp[2 * m] = l0 - ls;
        outp[2 * m + 1] = l1 - ls;
        if (feat) feat[m] = (l1 > l0) ? 1.f : 0.f;
    }
}

__global__ void k_label(const int* __restrict__ l3, float* __restrict__ out) {
    int e = blockIdx.x, c = threadIdx.x;
    int a = l3[e * 3], b = l3[e * 3 + 1], d = l3[e * 3 + 2];
    out[e * 256 + c] = (a == c || b == c || d == c) ? 1.f : 0.f;
}

// ---------------------------------------------------------------- host
extern "C" void kernel_launch(void* const* d_in, const int* in_sizes, int n_in,
                              void* d_out, int out_size, void* d_ws, size_t ws_size,
                              hipStream_t stream) {
    (void)in_sizes; (void)n_in; (void)out_size; (void)ws_size;
    const float* word = (const float*)d_in[0];
    const float* pos = (const float*)d_in[1];
    const float* dis = (const float*)d_in[2];
    const float* WihF = (const float*)d_in[3];
    const float* WhhF = (const float*)d_in[4];
    const float* bihF = (const float*)d_in[5];
    const float* bhhF = (const float*)d_in[6];
    const float* WihB = (const float*)d_in[7];
    const float* WhhB = (const float*)d_in[8];
    const float* bihB = (const float*)d_in[9];
    const float* bhhB = (const float*)d_in[10];
    const float* s1W = (const float*)d_in[11];
    const float* s1b = (const float*)d_in[12];
    const float* s2W = (const float*)d_in[13];
    const float* repW = (const float*)d_in[14];
    const float* repb = (const float*)d_in[15];
    const float* W2W = (const float*)d_in[16];
    const float* W2b = (const float*)d_in[17];
    const float* WoW = (const float*)d_in[18];
    const float* Wob = (const float*)d_in[19];
    const float* W3W = (const float*)d_in[20];
    const float* W3b = (const float*)d_in[21];
    const float* clsW = (const float*)d_in[22];
    const float* clsb = (const float*)d_in[23];
    const int* slen = (const int*)d_in[24];
    const int* emo = (const int*)d_in[25];
    const int* cau = (const int*)d_in[26];
    const int* lab3 = (const int*)d_in[27];
    float* out = (float*)d_out;

    char* ws = (char*)d_ws;
    size_t off = 0;
    auto alloc = [&](size_t b) -> char* {
        char* p = ws + off;
        off += (b + 255) & ~(size_t)255;
        return p;
    };
    float* biasF = (float*)alloc(1536 * 4);
    float* biasB = (float*)alloc(1536 * 4);
    float* wpF = (float*)alloc((size_t)384 * 1536 * 4);
    float* wpB = (float*)alloc((size_t)384 * 1536 * 4);
    float* s1T = (float*)alloc((size_t)768 * 768 * 4);
    float* repT = (float*)alloc((size_t)768 * 768 * 4);
    float* W2aT = (float*)alloc((size_t)768 * 768 * 4);
    float* W3aT = (float*)alloc((size_t)768 * 768 * 4);
    float* W3bT = (float*)alloc((size_t)768 * 768 * 4);
    float* W3dT = (float*)alloc((size_t)768 * 768 * 4);
    float* B2cat = (float*)alloc((size_t)768 * 1600 * 4);
    float* hbuf = (float*)alloc((size_t)2 * 98304 * 4);  // [dir][256*384]
    float* cbuf = (float*)alloc((size_t)2 * 98304 * 4);
    float* Hsf = (float*)alloc((size_t)24576 * 768 * 4);  // 75.5 MB
    float* escoreP = (float*)alloc((size_t)24576 * 6 * 4);
    float* Uf = (float*)alloc((size_t)256 * 768 * 4);
    float* UcatF = (float*)alloc((size_t)384 * 768 * 4);
    float* CuEf = (float*)alloc((size_t)384 * 768 * 4);  // rows 0:256 Cu, 256:384 E
    float* scF = (float*)alloc((size_t)8192 * 4 * 4);
    float* nrm2F = (float*)alloc(8192 * 4);
    float* nrm3F = (float*)alloc(32768 * 4);
    float* E2F = (float*)alloc((size_t)128 * 768 * 4);
    float* E3F = (float*)alloc((size_t)128 * 768 * 4);
    float* Bv3F = (float*)alloc((size_t)256 * 768 * 4);
    float* mean2 = (float*)alloc((size_t)128 * 768 * 4);
    float* rstd2 = (float*)alloc((size_t)128 * 768 * 4);
    float* mean3 = (float*)alloc((size_t)128 * 768 * 4);
    float* rstd3 = (float*)alloc((size_t)128 * 768 * 4);
    float* outfeatF = (float*)alloc(8192 * 4);
    char* BIG = alloc((size_t)103 * 1024 * 1024);

    float* gchF = (float*)BIG;                      // [8192,1536] f32 = 50.33 MB
    float* gchB = (float*)(BIG + (size_t)50331648);
    float* ceF = (float*)BIG;                       // [8192,768] f32 = 25.17 MB
    float* z2F = (float*)(BIG + (size_t)25165824);  // [8192,768] f32
    float* z3F = (float*)BIG;                       // [32768,768] f32 = 100.7 MB

    // ---- init h0 = c0 = 0 (hbuf and cbuf are contiguous)
    hipMemsetAsync(hbuf, 0, (size_t)4 * 98304 * 4, stream);

    // ---- weight prep
    k_bias2<<<6, 256, 0, stream>>>(bihF, bhhF, biasF, 1536);
    k_bias2<<<6, 256, 0, stream>>>(bihB, bhhB, biasB, 1536);
    k_wpack<<<2304, 256, 0, stream>>>(WhhF, wpF);
    k_wpack<<<2304, 256, 0, stream>>>(WhhB, wpB);
    k_transp32<<<dim3(24, 24), 256, 0, stream>>>(s1W, s1T, 0);
    k_transp32<<<dim3(24, 24), 256, 0, stream>>>(repW, repT, 0);
    k_transp32<<<dim3(24, 24), 256, 0, stream>>>(W2W, W2aT, 0);
    k_transp32<<<dim3(24, 24), 256, 0, stream>>>(W3W, W3aT, 0);
    k_transp32<<<dim3(24, 24), 256, 0, stream>>>(W3W, W3bT, 768);
    k_transp32<<<dim3(24, 24), 256, 0, stream>>>(W3W, W3dT, 1537);
    k_b2cat32<<<dim3(24, 50), 256, 0, stream>>>(W2W, B2cat);

    // ---- LSTM: 3 chunks {2 gate GEMMs + 1 sync-free row-partitioned kernel}
    for (int c = 0; c < 3; c++) {
        {
            G32 g{};
            g.A = word; g.B = WihF; g.bias = biasF; g.out = gchF; g.slen = slen;
            g.M = 8192; g.N = 1536; g.K = 768; g.lda = 768; g.ldb = 768; g.ldc = 1536;
            g.c0 = c * 32;
            k_gemm32<1, 0><<<dim3(12, 64), 512, 0, stream>>>(g);
            g.B = WihB; g.bias = biasB; g.out = gchB;
            k_gemm32<3, 0><<<dim3(12, 64), 512, 0, stream>>>(g);
        }
        k_lstm_rows<<<128, 384, 0, stream>>>(gchF, gchB, wpF, wpB,
                                             hbuf, cbuf, Hsf, slen, c * 32);
    }

    // ---- attention scores (fixed-order partials, no atomics)
    {
        G32 g{};
        g.A = Hsf; g.B = s1T; g.bias = s1b; g.s2v = s2W; g.escoreP = escoreP;
        g.M = 24576; g.N = 768; g.K = 768; g.lda = 768; g.ldb = 768; g.ldc = 768;
        k_gemm32<0, 3><<<dim3(6, 192), 512, 0, stream>>>(g);
    }
    k_alpha_u<<<256, 256, 0, stream>>>(escoreP, Hsf, slen, Uf);
    k_ucat<<<(384 * 768 + 255) / 256, 256, 0, stream>>>(Uf, cau, emo, UcatF);

    // ---- Cu / E = lrelu(U[idx] @ rep + b)
    {
        G32 g{};
        g.A = UcatF; g.B = repT; g.bias = repb; g.out = CuEf;
        g.M = 384; g.N = 768; g.K = 768; g.lda = 768; g.ldb = 768; g.ldc = 768;
        k_gemm32<0, 2><<<dim3(6, 3), 512, 0, stream>>>(g);
    }

    // ---- chunk attention
    k_chunk_sc<<<8192, 256, 0, stream>>>(CuEf, scF);
    k_chunk_emb<<<(8192 * 768 + 255) / 256, 256, 0, stream>>>(scF, CuEf, ceF);

    // ---- phase 2
    k_nrm2<<<8192, 256, 0, stream>>>(ceF, CuEf, nrm2F);
    {
        G32 g{};
        g.A = CuEf + (size_t)256 * 768; g.B = W2aT; g.out = E2F;
        g.M = 128; g.N = 768; g.K = 768; g.lda = 768; g.ldb = 768; g.ldc = 768;
        k_gemm32<0, 0><<<dim3(6, 1), 512, 0, stream>>>(g);
    }
    {
        G32 g{};
        g.B = B2cat; g.out = z2F; g.bias = W2b;
        g.addE = E2F; g.nrm = nrm2F; g.wn = W2W + (size_t)1536 * 768;
        g.ce = ceF; g.CuEf = CuEf; g.pos = pos;
        g.M = 8192; g.N = 768; g.K = 1600; g.ldb = 1600; g.ldc = 768;
        k_gemm32<4, 4><<<dim3(6, 64), 512, 0, stream>>>(g);
    }
    k_bnstats<64><<<384, 256, 0, stream>>>(z2F, mean2, rstd2);
    k_bn_head<64><<<8192, 256, 0, stream>>>(z2F, mean2, rstd2, WoW, Wob, out, outfeatF);

    // ---- phase 3
    k_nrm3<<<32768, 256, 0, stream>>>(CuEf, nrm3F);
    {
        G32 g{};
        g.A = CuEf; g.B = W3bT; g.out = Bv3F;
        g.M = 256; g.N = 768; g.K = 768; g.lda = 768; g.ldb = 768; g.ldc = 768;
        k_gemm32<0, 0><<<dim3(6, 2), 512, 0, stream>>>(g);
    }
    k_bv3_dis<<<(256 * 768 + 255) / 256, 256, 0, stream>>>(Bv3F, dis, W3W, W3b);
    {
        G32 g{};
        g.A = CuEf + (size_t)256 * 768; g.B = W3aT; g.out = E3F;
        g.M = 128; g.N = 768; g.K = 768; g.lda = 768; g.ldb = 768; g.ldc = 768;
        k_gemm32<0, 0><<<dim3(6, 1), 512, 0, stream>>>(g);
    }
    {
        G32 g{};
        g.B = W3dT; g.out = z3F;
        g.addE = E3F; g.addB = Bv3F; g.nrm = nrm3F; g.wn = W3W + (size_t)1536 * 768;
        g.feat = outfeatF; g.wx = W3W + (size_t)2355 * 768;
        g.CuEf = CuEf;
        g.M = 32768; g.N = 768; g.K = 768; g.ldb = 768; g.ldc = 768;
        k_gemm32<2, 5><<<dim3(6, 256), 512, 0, stream>>>(g);
    }
    k_bnstats<256><<<384, 256, 0, stream>>>(z3F, mean3, rstd3);
    k_bn_head<256><<<32768, 256, 0, stream>>>(z3F, mean3, rstd3, clsW, clsb, out + 16384, nullptr);

    // ---- L
    k_label<<<128, 256, 0, stream>>>(lab3, out + 81920);
}